// Round 11
// baseline (1566.623 us; speedup 1.0000x reference)
//
#include <hip/hip_runtime.h>
#include <hip/hip_bf16.h>

// GCN 2-layer surrogate. Fixed-capacity bucket partition + per-bucket
// LDS-accumulator aggregation (no CSR sort).
//   bucket = dst >> 8 (391 buckets x 256 nodes), fixed capacity BCAP/bucket
//   part:  bin edges by bucket (int4 loads); per-(block,bucket) gCursor claim,
//          per-edge LDS-cursor claim, direct scattered store of packed int
//          src | (dst&255)<<20 into bucket region b*BCAP  (no staging, no scan)
//   degs:  per-bucket node histogram -> dinv = rsqrt(deg+1)
//   gemm1: MFMA bf16: hs_bf16 = bf16( dinv[r] * (x @ W1) )   (12.8 MB table)
//   agg1b: per bucket (1024 thr): LDS f32 acc[256][65]; thread-per-(edge,octet),
//          uint4 row gather + 8x ds_add_f32; fused relu + (64->2) + pre-scale
//   agg2b: per bucket: LDS acc2[256][2]; thread-per-edge float2 gather of hs2
//          (L2-resident 800 KB table); fused epilogue

#define N_NODES 100000
#define IN_DIM 128
#define HID_DIM 64
#define OUT_DIM 2
#define NB 391          // ceil(100000/256)
#define BCAP 12288      // slots per bucket (mean 8184, sigma ~90 -> 45 sigma)
#define CHUNK 8192
#define ASTRIDE 65      // acc row stride (odd -> bank spread)

typedef short bf16x8 __attribute__((ext_vector_type(8)));
typedef float f32x4 __attribute__((ext_vector_type(4)));

__device__ __forceinline__ unsigned short f2bf(float x) {
    unsigned int u = __float_as_uint(x);
    unsigned int r = (u + 0x7FFFu + ((u >> 16) & 1u)) >> 16;   // RNE
    return (unsigned short)r;
}
__device__ __forceinline__ float bflo(unsigned int u) { return __uint_as_float(u << 16); }
__device__ __forceinline__ float bfhi(unsigned int u) { return __uint_as_float(u & 0xFFFF0000u); }

// ---------------- part: direct-claim partition into bucket regions ----------------
__global__ __launch_bounds__(512) void part_kernel(const int* __restrict__ ei,
                                                   int* __restrict__ gCursor,
                                                   int* __restrict__ part, int E) {
    __shared__ int hist[512];
    __shared__ int lcur[512];
    const int t = threadIdx.x;
    const int base = blockIdx.x * CHUNK;

    hist[t] = 0;
    __syncthreads();

    int s[16], d[16];
    bool val[16];
    if (base + CHUNK <= E) {
#pragma unroll
        for (int i = 0; i < 4; ++i) {
            int4 sv = ((const int4*)(ei + base))[t + i * 512];
            int4 dv = ((const int4*)(ei + E + base))[t + i * 512];
            s[i * 4 + 0] = sv.x; s[i * 4 + 1] = sv.y; s[i * 4 + 2] = sv.z; s[i * 4 + 3] = sv.w;
            d[i * 4 + 0] = dv.x; d[i * 4 + 1] = dv.y; d[i * 4 + 2] = dv.z; d[i * 4 + 3] = dv.w;
            val[i * 4 + 0] = val[i * 4 + 1] = val[i * 4 + 2] = val[i * 4 + 3] = true;
        }
    } else {
#pragma unroll
        for (int i = 0; i < 16; ++i) {
            int e = base + t + i * 512;
            val[i] = (e < E);
            if (val[i]) {
                s[i] = ei[e];
                d[i] = ei[E + e];
            }
        }
    }
#pragma unroll
    for (int i = 0; i < 16; ++i)
        if (val[i]) atomicAdd(&hist[d[i] >> 8], 1);
    __syncthreads();

    if (t < NB) {
        int v = hist[t];
        if (v > 0) lcur[t] = t * BCAP + atomicAdd(&gCursor[t], v);
    }
    __syncthreads();

#pragma unroll
    for (int i = 0; i < 16; ++i) {
        if (val[i]) {
            int b = d[i] >> 8;
            int pos = atomicAdd(&lcur[b], 1);
            if (pos < (b + 1) * BCAP)      // overflow guard (never in practice)
                part[pos] = s[i] | ((d[i] & 255) << 20);
        }
    }
}

// ---------------- degs: per-bucket node histogram -> dinv ----------------
__global__ __launch_bounds__(256) void degs_kernel(const int* __restrict__ part,
                                                   const int* __restrict__ gCursor,
                                                   float* __restrict__ dinv, int n) {
    __shared__ int lcnt[256];
    const int b = blockIdx.x, t = threadIdx.x;
    const int start = b * BCAP;
    const int count = min(gCursor[b], BCAP);
    lcnt[t] = 0;
    __syncthreads();
    for (int i = t; i < count; i += 256)
        atomicAdd(&lcnt[(part[start + i] >> 20) & 255], 1);
    __syncthreads();
    int node = (b << 8) + t;
    if (node < n) dinv[node] = rsqrtf((float)lcnt[t] + 1.0f);
}

// ---------------- GEMM1 (MFMA bf16): hs_bf16 = bf16(dinv[r] * (x @ W1)) ----------------
__global__ __launch_bounds__(256) void gemm1_kernel(const float* __restrict__ x,
                                                    const float* __restrict__ W1,
                                                    const float* __restrict__ dinv,
                                                    unsigned short* __restrict__ hsb, int n) {
    __shared__ unsigned short sX[64 * 136];   // 17.4 KB
    __shared__ unsigned short sW[64 * 136];   // 17.4 KB (transposed W1)
    const int tid = threadIdx.x;
    const int rbase = blockIdx.x * 64;

    // stage W1^T: read [k][c] coalesced as float4, scatter bf16 to [c][k]
    for (int i = tid; i < 2048; i += 256) {
        int k = i >> 4, cq = (i & 15) << 2;
        float4 v = ((const float4*)W1)[i];
        sW[(cq + 0) * 136 + k] = f2bf(v.x);
        sW[(cq + 1) * 136 + k] = f2bf(v.y);
        sW[(cq + 2) * 136 + k] = f2bf(v.z);
        sW[(cq + 3) * 136 + k] = f2bf(v.w);
    }
    // stage x rows as bf16 (row-major, pad 136)
    for (int i = tid; i < 2048; i += 256) {
        int r = i >> 5, kq = (i & 31) << 2;
        int gr = rbase + r;
        float4 v = make_float4(0.f, 0.f, 0.f, 0.f);
        if (gr < n) v = ((const float4*)x)[gr * 32 + (i & 31)];
        ushort4 u;
        u.x = f2bf(v.x); u.y = f2bf(v.y); u.z = f2bf(v.z); u.w = f2bf(v.w);
        *(ushort4*)&sX[r * 136 + kq] = u;
    }
    __syncthreads();

    const int wave = tid >> 6, lane = tid & 63;
    const int quad = lane >> 4, l16 = lane & 15;
    const int rowoff = wave * 16;

    f32x4 acc[4];
#pragma unroll
    for (int t = 0; t < 4; ++t) acc[t] = (f32x4){0.f, 0.f, 0.f, 0.f};

#pragma unroll
    for (int k0 = 0; k0 < 128; k0 += 32) {
        bf16x8 a = *(const bf16x8*)&sX[(rowoff + l16) * 136 + k0 + quad * 8];
#pragma unroll
        for (int t = 0; t < 4; ++t) {
            bf16x8 b = *(const bf16x8*)&sW[(t * 16 + l16) * 136 + k0 + quad * 8];
            acc[t] = __builtin_amdgcn_mfma_f32_16x16x32_bf16(a, b, acc[t], 0, 0, 0);
        }
    }

    // D layout: col = l16, row = quad*4 + reg
#pragma unroll
    for (int r = 0; r < 4; ++r) {
        int grow = rbase + rowoff + quad * 4 + r;
        if (grow < n) {
            float di = dinv[grow];
#pragma unroll
            for (int t = 0; t < 4; ++t)
                hsb[grow * HID_DIM + t * 16 + l16] = f2bf(acc[t][r] * di);
        }
    }
}

// ---------------- agg1b: per-bucket LDS-accumulator aggregation + fused epilogue ----------------
// thread-per-(edge, dim-octet): lane l = t&7 handles dims l*8..l*8+7 of edge t>>3 (+128 step).
__global__ __launch_bounds__(1024) void agg1b_kernel(const int* __restrict__ part,
                                                     const int* __restrict__ gCursor,
                                                     const unsigned short* __restrict__ hsb,
                                                     const float* __restrict__ dinv,
                                                     const float* __restrict__ b1,
                                                     const float* __restrict__ W2,
                                                     float* __restrict__ hs2, int n) {
    __shared__ float acc[256 * ASTRIDE];     // 66.6 KB
    __shared__ int lpk[2048];                // 8 KB
    const int b = blockIdx.x, t = threadIdx.x;
    const int start = b * BCAP;
    const int count = min(gCursor[b], BCAP);

    for (int i = t; i < 256 * ASTRIDE; i += 1024) acc[i] = 0.0f;
    __syncthreads();

    const int l = t & 7, eb = t >> 3;
    for (int c0 = 0; c0 < count; c0 += 2048) {
        int m = min(2048, count - c0);
        for (int i = t; i < m; i += 1024) lpk[i] = part[start + c0 + i];
        __syncthreads();
#pragma unroll 4
        for (int e = eb; e < m; e += 128) {
            int p = lpk[e];
            int sIdx = p & 0xFFFFF;
            int ld = (p >> 20) & 255;
            uint4 r = *(const uint4*)&hsb[(unsigned)sIdx * HID_DIM + l * 8];
            float* ap = &acc[ld * ASTRIDE + l * 8];
            atomicAdd(ap + 0, bflo(r.x)); atomicAdd(ap + 1, bfhi(r.x));
            atomicAdd(ap + 2, bflo(r.y)); atomicAdd(ap + 3, bfhi(r.y));
            atomicAdd(ap + 4, bflo(r.z)); atomicAdd(ap + 5, bfhi(r.z));
            atomicAdd(ap + 6, bflo(r.w)); atomicAdd(ap + 7, bfhi(r.w));
        }
        __syncthreads();
    }

    // epilogue: 4 threads/node, 16 dims each
    const int node = t >> 2, q = t & 3;
    const int gnode = (b << 8) + node;
    if (gnode < n) {
        float di = dinv[gnode];
        const float* ar = &acc[node * ASTRIDE + q * 16];
        const unsigned short* hr = &hsb[(unsigned)gnode * HID_DIM + q * 16];
        uint4 s0 = *(const uint4*)(hr);
        uint4 s1 = *(const uint4*)(hr + 8);
        float selfv[16] = {
            bflo(s0.x), bfhi(s0.x), bflo(s0.y), bfhi(s0.y),
            bflo(s0.z), bfhi(s0.z), bflo(s0.w), bfhi(s0.w),
            bflo(s1.x), bfhi(s1.x), bflo(s1.y), bfhi(s1.y),
            bflo(s1.z), bfhi(s1.z), bflo(s1.w), bfhi(s1.w)};
        float p0 = 0.f, p1 = 0.f;
#pragma unroll
        for (int k = 0; k < 16; ++k) {
            int dim = q * 16 + k;
            float tv = fmaxf(fmaf(di, ar[k] + selfv[k], b1[dim]), 0.0f);
            p0 = fmaf(tv, W2[dim * OUT_DIM + 0], p0);
            p1 = fmaf(tv, W2[dim * OUT_DIM + 1], p1);
        }
        p0 += __shfl_xor(p0, 1);  p1 += __shfl_xor(p1, 1);
        p0 += __shfl_xor(p0, 2);  p1 += __shfl_xor(p1, 2);
        if (q == 0) {
            hs2[gnode * OUT_DIM + 0] = di * p0;
            hs2[gnode * OUT_DIM + 1] = di * p1;
        }
    }
}

// ---------------- agg2b: per-bucket LDS d=2 accumulate + fused epilogue ----------------
__global__ __launch_bounds__(1024) void agg2b_kernel(const int* __restrict__ part,
                                                     const int* __restrict__ gCursor,
                                                     const float* __restrict__ hs2,
                                                     const float* __restrict__ dinv,
                                                     const float* __restrict__ b2,
                                                     float* __restrict__ out, int n) {
    __shared__ float acc2[256 * OUT_DIM];    // 2 KB
    __shared__ int lpk[2048];                // 8 KB
    const int b = blockIdx.x, t = threadIdx.x;
    const int start = b * BCAP;
    const int count = min(gCursor[b], BCAP);

    if (t < 512) acc2[t] = 0.0f;
    __syncthreads();

    for (int c0 = 0; c0 < count; c0 += 2048) {
        int m = min(2048, count - c0);
        for (int i = t; i < m; i += 1024) lpk[i] = part[start + c0 + i];
        __syncthreads();
        for (int e = t; e < m; e += 1024) {
            int p = lpk[e];
            int sIdx = p & 0xFFFFF;
            int ld = (p >> 20) & 255;
            float2 v = *(const float2*)&hs2[sIdx * OUT_DIM];
            atomicAdd(&acc2[ld * OUT_DIM + 0], v.x);
            atomicAdd(&acc2[ld * OUT_DIM + 1], v.y);
        }
        __syncthreads();
    }

    int node = (b << 8) + t;
    if (t < 256 && node < n) {
        float di = dinv[node];
        float2 self = *(const float2*)&hs2[node * OUT_DIM];
        out[node * OUT_DIM + 0] = di * (acc2[t * OUT_DIM + 0] + self.x) + b2[0];
        out[node * OUT_DIM + 1] = di * (acc2[t * OUT_DIM + 1] + self.y) + b2[1];
    }
}

extern "C" void kernel_launch(void* const* d_in, const int* in_sizes, int n_in,
                              void* d_out, int out_size, void* d_ws, size_t ws_size,
                              hipStream_t stream) {
    const float* x  = (const float*)d_in[0];
    const int*   ei = (const int*)d_in[1];     // [2][E], row 0 = src, row 1 = dst
    const float* W1 = (const float*)d_in[2];
    const float* b1 = (const float*)d_in[3];
    const float* W2 = (const float*)d_in[4];
    const float* b2 = (const float*)d_in[5];
    float* out = (float*)d_out;

    const int n = N_NODES;
    const int E = in_sizes[1] / 2;

    char* ws = (char*)d_ws;
    int*   gCursor = (int*)  (ws + 0);            // 1.6 KB
    float* dinv    = (float*)(ws + (1u << 20));   // 400 KB
    float* hs2     = (float*)(ws + (2u << 20));   // 800 KB
    int*   part    = (int*)  (ws + (5u << 20));   // NB*BCAP*4 = 18.3 MB (live through agg2b)
    unsigned short* hsb = (unsigned short*)(ws + (24u << 20));  // 12.8 MB

    hipMemsetAsync(gCursor, 0, NB * sizeof(int), stream);

    part_kernel<<<(E + CHUNK - 1) / CHUNK, 512, 0, stream>>>(ei, gCursor, part, E);
    degs_kernel<<<NB, 256, 0, stream>>>(part, gCursor, dinv, n);

    gemm1_kernel<<<(n + 63) / 64, 256, 0, stream>>>(x, W1, dinv, hsb, n);
    agg1b_kernel<<<NB, 1024, 0, stream>>>(part, gCursor, hsb, dinv, b1, W2, hs2, n);
    agg2b_kernel<<<NB, 1024, 0, stream>>>(part, gCursor, hs2, dinv, b2, out, n);
}

// Round 12
// 243.641 us; speedup vs baseline: 6.4300x; 6.4300x over previous
//
#include <hip/hip_runtime.h>
#include <hip/hip_bf16.h>

// GCN 2-layer surrogate. Fixed-capacity bucket partition + fused
// sort-in-LDS + gather-reduce aggregation.
//   bucket = dst >> 7 (782 buckets x 128 nodes), fixed capacity BCAP/bucket
//   part:    bin edges by bucket (int4 loads), staged write-out of packed int
//            src | (dst&127)<<20 into bucket region b*BCAP
//   degs:    per-bucket node histogram -> dinv = rsqrt(deg+1)   (pre-gemm1)
//   gemm1:   MFMA bf16: hs_bf16 = bf16( dinv[r] * (x @ W1) )    (12.8 MB table)
//   aggsort: block per bucket (512 thr): LDS counting sort (wave-private hists)
//            -> cnt/rowptr/csr_src; then R10-style register gather-reduce
//            (4 uint4 gathers in flight, indices from LDS) + fused epilogue
//   agg2:    2 nodes per wave, lane-parallel edges on d=2 table (sorted lists)

#define N_NODES 100000
#define IN_DIM 128
#define HID_DIM 64
#define OUT_DIM 2
#define NB 782          // ceil(100000/128) buckets of 128 nodes
#define BCAP 5120       // slots per bucket (mean 4092, sigma ~64 -> +16 sigma)
#define CHUNK 8192

typedef short bf16x8 __attribute__((ext_vector_type(8)));
typedef float f32x4 __attribute__((ext_vector_type(4)));

__device__ __forceinline__ unsigned short f2bf(float x) {
    unsigned int u = __float_as_uint(x);
    unsigned int r = (u + 0x7FFFu + ((u >> 16) & 1u)) >> 16;   // RNE
    return (unsigned short)r;
}
__device__ __forceinline__ float bflo(unsigned int u) { return __uint_as_float(u << 16); }
__device__ __forceinline__ float bfhi(unsigned int u) { return __uint_as_float(u & 0xFFFF0000u); }
__device__ __forceinline__ float4 unplo(uint4 r) {
    return make_float4(bflo(r.x), bflo(r.y), bflo(r.z), bflo(r.w));
}
__device__ __forceinline__ float4 unphi(uint4 r) {
    return make_float4(bfhi(r.x), bfhi(r.y), bfhi(r.z), bfhi(r.w));
}
__device__ __forceinline__ float4 f4add(float4 a, float4 v) {
    return make_float4(a.x + v.x, a.y + v.y, a.z + v.z, a.w + v.w);
}
__device__ __forceinline__ float4 f4fma(float m, float4 v, float4 a) {
    return make_float4(fmaf(m, v.x, a.x), fmaf(m, v.y, a.y),
                       fmaf(m, v.z, a.z), fmaf(m, v.w, a.w));
}
__device__ __forceinline__ int wave_incl_scan(int v, int laneid) {
#pragma unroll
    for (int off = 1; off < 64; off <<= 1) {
        int u = __shfl_up(v, off);
        if (laneid >= off) v += u;
    }
    return v;
}

// ---------------- part: staged partition into fixed-capacity bucket regions ----------------
__global__ __launch_bounds__(1024) void part_kernel(const int* __restrict__ ei,
                                                    int* __restrict__ gCursor,
                                                    int* __restrict__ part, int E) {
    __shared__ int hist[1024], lrow[1024], gbase[1024], lcur[1024];
    __shared__ int lpk[CHUNK];
    __shared__ short lbkt[CHUNK];
    __shared__ int wsum[16], wofs[16];
    const int t = threadIdx.x;
    const int lane = t & 63, wv = t >> 6;
    const int base = blockIdx.x * CHUNK;
    const int cntC = min(CHUNK, E - base);

    hist[t] = 0;
    __syncthreads();

    int s[8], d[8];
    bool val[8];
    if (base + CHUNK <= E) {
#pragma unroll
        for (int i = 0; i < 2; ++i) {
            int4 sv = ((const int4*)(ei + base))[t + i * 1024];
            int4 dv = ((const int4*)(ei + E + base))[t + i * 1024];
            s[i * 4 + 0] = sv.x; s[i * 4 + 1] = sv.y; s[i * 4 + 2] = sv.z; s[i * 4 + 3] = sv.w;
            d[i * 4 + 0] = dv.x; d[i * 4 + 1] = dv.y; d[i * 4 + 2] = dv.z; d[i * 4 + 3] = dv.w;
            val[i * 4 + 0] = val[i * 4 + 1] = val[i * 4 + 2] = val[i * 4 + 3] = true;
        }
    } else {
#pragma unroll
        for (int i = 0; i < 8; ++i) {
            int e = base + t + i * 1024;
            val[i] = (e < E);
            if (val[i]) {
                s[i] = ei[e];
                d[i] = ei[E + e];
            }
        }
    }
#pragma unroll
    for (int i = 0; i < 8; ++i)
        if (val[i]) atomicAdd(&hist[d[i] >> 7], 1);
    __syncthreads();

    int v = hist[t];
    int inc = wave_incl_scan(v, lane);
    if (lane == 63) wsum[wv] = inc;
    __syncthreads();
    if (t < 64) {
        int w = (t < 16) ? wsum[t] : 0;
        int wi = wave_incl_scan(w, t);
        if (t < 16) wofs[t] = wi - w;
    }
    __syncthreads();
    int excl = inc - v + wofs[wv];
    if (t < NB && v > 0) {
        int old = atomicAdd(&gCursor[t], v);
        gbase[t] = t * BCAP + old;
    }
    lcur[t] = excl;
    lrow[t] = excl;                    // exclusive offsets for write-out
    __syncthreads();

#pragma unroll
    for (int i = 0; i < 8; ++i) {
        if (val[i]) {
            int b = d[i] >> 7;
            int pos = atomicAdd(&lcur[b], 1);
            lpk[pos] = s[i] | ((d[i] & 127) << 20);
            lbkt[pos] = (short)b;
        }
    }
    __syncthreads();

    for (int i = t; i < cntC; i += 1024) {
        int b = lbkt[i];
        int g = gbase[b] + (i - lrow[b]);
        if (g < (b + 1) * BCAP)        // overflow guard (never in practice)
            part[g] = lpk[i];
    }
}

// ---------------- degs: per-bucket node histogram -> dinv (needed by gemm1) ----------------
__global__ __launch_bounds__(256) void degs_kernel(const int* __restrict__ part,
                                                   const int* __restrict__ gCursor,
                                                   float* __restrict__ dinv, int n) {
    __shared__ int lcnt[128];
    const int b = blockIdx.x, t = threadIdx.x;
    const int start = b * BCAP;
    const int count = min(gCursor[b], BCAP);
    if (t < 128) lcnt[t] = 0;
    __syncthreads();
    for (int i = t; i < count; i += 256)
        atomicAdd(&lcnt[(part[start + i] >> 20) & 127], 1);
    __syncthreads();
    int node = (b << 7) + t;
    if (t < 128 && node < n) dinv[node] = rsqrtf((float)lcnt[t] + 1.0f);
}

// ---------------- GEMM1 (MFMA bf16): hs_bf16 = bf16(dinv[r] * (x @ W1)) ----------------
__global__ __launch_bounds__(256) void gemm1_kernel(const float* __restrict__ x,
                                                    const float* __restrict__ W1,
                                                    const float* __restrict__ dinv,
                                                    unsigned short* __restrict__ hsb, int n) {
    __shared__ unsigned short sX[64 * 136];   // 17.4 KB
    __shared__ unsigned short sW[64 * 136];   // 17.4 KB (transposed W1)
    const int tid = threadIdx.x;
    const int rbase = blockIdx.x * 64;

    // stage W1^T: read [k][c] coalesced as float4, scatter bf16 to [c][k]
    for (int i = tid; i < 2048; i += 256) {
        int k = i >> 4, cq = (i & 15) << 2;
        float4 v = ((const float4*)W1)[i];
        sW[(cq + 0) * 136 + k] = f2bf(v.x);
        sW[(cq + 1) * 136 + k] = f2bf(v.y);
        sW[(cq + 2) * 136 + k] = f2bf(v.z);
        sW[(cq + 3) * 136 + k] = f2bf(v.w);
    }
    // stage x rows as bf16 (row-major, pad 136)
    for (int i = tid; i < 2048; i += 256) {
        int r = i >> 5, kq = (i & 31) << 2;
        int gr = rbase + r;
        float4 v = make_float4(0.f, 0.f, 0.f, 0.f);
        if (gr < n) v = ((const float4*)x)[gr * 32 + (i & 31)];
        ushort4 u;
        u.x = f2bf(v.x); u.y = f2bf(v.y); u.z = f2bf(v.z); u.w = f2bf(v.w);
        *(ushort4*)&sX[r * 136 + kq] = u;
    }
    __syncthreads();

    const int wave = tid >> 6, lane = tid & 63;
    const int quad = lane >> 4, l16 = lane & 15;
    const int rowoff = wave * 16;

    f32x4 acc[4];
#pragma unroll
    for (int t = 0; t < 4; ++t) acc[t] = (f32x4){0.f, 0.f, 0.f, 0.f};

#pragma unroll
    for (int k0 = 0; k0 < 128; k0 += 32) {
        bf16x8 a = *(const bf16x8*)&sX[(rowoff + l16) * 136 + k0 + quad * 8];
#pragma unroll
        for (int t = 0; t < 4; ++t) {
            bf16x8 b = *(const bf16x8*)&sW[(t * 16 + l16) * 136 + k0 + quad * 8];
            acc[t] = __builtin_amdgcn_mfma_f32_16x16x32_bf16(a, b, acc[t], 0, 0, 0);
        }
    }

    // D layout: col = l16, row = quad*4 + reg
#pragma unroll
    for (int r = 0; r < 4; ++r) {
        int grow = rbase + rowoff + quad * 4 + r;
        if (grow < n) {
            float di = dinv[grow];
#pragma unroll
            for (int t = 0; t < 4; ++t)
                hsb[grow * HID_DIM + t * 16 + l16] = f2bf(acc[t][r] * di);
        }
    }
}

// ---------------- aggsort: LDS counting sort + register gather-reduce + epilogue ----------------
// 512 threads = 8 waves; 128 nodes/bucket; each wave handles 16 nodes.
__global__ __launch_bounds__(512) void aggsort_kernel(const int* __restrict__ part,
                                                      const int* __restrict__ gCursor,
                                                      const unsigned short* __restrict__ hsb,
                                                      const float* __restrict__ dinv,
                                                      const float* __restrict__ b1,
                                                      const float* __restrict__ W2,
                                                      int* __restrict__ cnt,
                                                      int* __restrict__ rowptr,
                                                      int* __restrict__ csr_src,
                                                      float* __restrict__ hs2, int n) {
    __shared__ int epk[BCAP];          // 20 KB raw packed edges
    __shared__ int sl[BCAP];           // 20 KB node-sorted src list
    __shared__ int wcnt[8][128];       // 4 KB per-wave hist -> per-wave bases
    __shared__ int lrow[128], lcnt[128];
    __shared__ int wsum[2];
    const int b = blockIdx.x, t = threadIdx.x;
    const int lane = t & 63, wv = t >> 6;
    const int start = b * BCAP;
    const int count = min(gCursor[b], BCAP);

    for (int i = t; i < 8 * 128; i += 512) ((int*)wcnt)[i] = 0;
    __syncthreads();

    // load + per-wave histogram
    for (int i = t; i < count; i += 512) {
        int p = part[start + i];
        epk[i] = p;
        atomicAdd(&wcnt[wv][(p >> 20) & 127], 1);
    }
    __syncthreads();

    // 128-entry scan (waves 0-1)
    int v = 0, inc = 0;
    if (t < 128) {
        int sum = 0;
#pragma unroll
        for (int w = 0; w < 8; ++w) sum += wcnt[w][t];
        v = sum;
        inc = wave_incl_scan(v, lane);
        if (lane == 63) wsum[t >> 6] = inc;
    }
    __syncthreads();
    if (t < 128) {
        int excl = inc - v + ((t >> 6) ? wsum[0] : 0);
        int node = (b << 7) + t;
        if (node < n) {
            cnt[node] = v;
            rowptr[node] = start + excl;
        }
        lcnt[t] = v;
        lrow[t] = excl;
        int run = excl;                // per-wave scatter bases, in place
#pragma unroll
        for (int w = 0; w < 8; ++w) {
            int c = wcnt[w][t];
            wcnt[w][t] = run;
            run += c;
        }
    }
    __syncthreads();

    // scatter into sorted list
    for (int i = t; i < count; i += 512) {
        int p = epk[i];
        int pos = atomicAdd(&wcnt[wv][(p >> 20) & 127], 1);
        sl[pos] = p & 0xFFFFF;
    }
    __syncthreads();

    // dump sorted list for agg2 (coalesced)
    for (int i = t; i < count; i += 512) csr_src[start + i] = sl[i];

    // gather-reduce: wave wv handles nodes wv*16 .. wv*16+15
    const int g = lane >> 3;       // edge group 0..7
    const int l = lane & 7;        // dim octet 0..7
    const float4 bb0 = *(const float4*)&b1[l * 8];
    const float4 bb1 = *(const float4*)&b1[l * 8 + 4];
    const float4 w0 = *(const float4*)&W2[l * 16];
    const float4 w1 = *(const float4*)&W2[l * 16 + 4];
    const float4 w2 = *(const float4*)&W2[l * 16 + 8];
    const float4 w3 = *(const float4*)&W2[l * 16 + 12];

    for (int nd = wv * 16; nd < wv * 16 + 16; ++nd) {
        int gnode = (b << 7) + nd;
        if (gnode >= n) break;
        int st = lrow[nd];
        int deg = lcnt[nd];

        float4 alo = make_float4(0.f, 0.f, 0.f, 0.f);
        float4 ahi = make_float4(0.f, 0.f, 0.f, 0.f);
        int s0 = (g      < deg) ? sl[st + g]      : 0;
        int s1 = (g +  8 < deg) ? sl[st + g +  8] : 0;
        int s2 = (g + 16 < deg) ? sl[st + g + 16] : 0;
        int s3 = (g + 24 < deg) ? sl[st + g + 24] : 0;
        for (int j = g; j < deg; j += 32) {
            int p0 = (j + 32 < deg) ? sl[st + j + 32] : 0;
            int p1 = (j + 40 < deg) ? sl[st + j + 40] : 0;
            int p2 = (j + 48 < deg) ? sl[st + j + 48] : 0;
            int p3 = (j + 56 < deg) ? sl[st + j + 56] : 0;
            uint4 r0 = *(const uint4*)&hsb[(unsigned)s0 * HID_DIM + l * 8];
            uint4 r1 = *(const uint4*)&hsb[(unsigned)s1 * HID_DIM + l * 8];
            uint4 r2 = *(const uint4*)&hsb[(unsigned)s2 * HID_DIM + l * 8];
            uint4 r3 = *(const uint4*)&hsb[(unsigned)s3 * HID_DIM + l * 8];
            float m1 = (j +  8 < deg) ? 1.0f : 0.0f;
            float m2 = (j + 16 < deg) ? 1.0f : 0.0f;
            float m3 = (j + 24 < deg) ? 1.0f : 0.0f;
            alo = f4add(alo, unplo(r0));      ahi = f4add(ahi, unphi(r0));
            alo = f4fma(m1, unplo(r1), alo);  ahi = f4fma(m1, unphi(r1), ahi);
            alo = f4fma(m2, unplo(r2), alo);  ahi = f4fma(m2, unphi(r2), ahi);
            alo = f4fma(m3, unplo(r3), alo);  ahi = f4fma(m3, unphi(r3), ahi);
            s0 = p0; s1 = p1; s2 = p2; s3 = p3;
        }

        float a[8];
        a[0] = alo.x; a[1] = ahi.x; a[2] = alo.y; a[3] = ahi.y;
        a[4] = alo.z; a[5] = ahi.z; a[6] = alo.w; a[7] = ahi.w;

        // combine the 8 edge-groups (dim octets identical across groups)
#pragma unroll
        for (int off = 8; off <= 32; off <<= 1) {
#pragma unroll
            for (int i = 0; i < 8; ++i) a[i] += __shfl_xor(a[i], off);
        }

        // self-loop term
        {
            uint4 raw = *(const uint4*)&hsb[(unsigned)gnode * HID_DIM + l * 8];
            a[0] += bflo(raw.x); a[1] += bfhi(raw.x);
            a[2] += bflo(raw.y); a[3] += bfhi(raw.y);
            a[4] += bflo(raw.z); a[5] += bfhi(raw.z);
            a[6] += bflo(raw.w); a[7] += bfhi(raw.w);
        }

        float di = dinv[gnode];
        float t0 = fmaxf(fmaf(di, a[0], bb0.x), 0.0f);
        float t1 = fmaxf(fmaf(di, a[1], bb0.y), 0.0f);
        float t2 = fmaxf(fmaf(di, a[2], bb0.z), 0.0f);
        float t3 = fmaxf(fmaf(di, a[3], bb0.w), 0.0f);
        float t4 = fmaxf(fmaf(di, a[4], bb1.x), 0.0f);
        float t5 = fmaxf(fmaf(di, a[5], bb1.y), 0.0f);
        float t6 = fmaxf(fmaf(di, a[6], bb1.z), 0.0f);
        float t7 = fmaxf(fmaf(di, a[7], bb1.w), 0.0f);

        float p0 = t0 * w0.x + t1 * w0.z + t2 * w1.x + t3 * w1.z
                 + t4 * w2.x + t5 * w2.z + t6 * w3.x + t7 * w3.z;
        float p1 = t0 * w0.y + t1 * w0.w + t2 * w1.y + t3 * w1.w
                 + t4 * w2.y + t5 * w2.w + t6 * w3.y + t7 * w3.w;
        p0 += __shfl_xor(p0, 1);  p1 += __shfl_xor(p1, 1);
        p0 += __shfl_xor(p0, 2);  p1 += __shfl_xor(p1, 2);
        p0 += __shfl_xor(p0, 4);  p1 += __shfl_xor(p1, 4);

        if (lane == 0) {
            hs2[gnode * OUT_DIM + 0] = di * p0;
            hs2[gnode * OUT_DIM + 1] = di * p1;
        }
    }
}

// ---------------- agg2: 2 nodes/wave CSR gather d=2 + fused epilogue ----------------
__global__ __launch_bounds__(256) void agg2_kernel(const int* __restrict__ rowptr,
                                                   const int* __restrict__ cnt,
                                                   const int* __restrict__ csr_src,
                                                   const float* __restrict__ hs2,
                                                   const float* __restrict__ dinv,
                                                   const float* __restrict__ b2,
                                                   float* __restrict__ out, int n) {
    int node = blockIdx.x * 8 + (threadIdx.x >> 5);
    if (node >= n) return;
    int lane = threadIdx.x & 31;
    int start = rowptr[node];
    int deg = cnt[node];

    float a0 = 0.0f, a1 = 0.0f;
    for (int j = lane; j < deg; j += 32) {
        int s = csr_src[start + j];
        float2 v = *(const float2*)&hs2[s * OUT_DIM];
        a0 += v.x;
        a1 += v.y;
    }
#pragma unroll
    for (int off = 16; off > 0; off >>= 1) {      // xor <=16 stays within 32-group
        a0 += __shfl_xor(a0, off);
        a1 += __shfl_xor(a1, off);
    }
    if (lane == 0) {
        float di = dinv[node];
        float2 self = *(const float2*)&hs2[node * OUT_DIM];
        out[node * OUT_DIM + 0] = di * (a0 + self.x) + b2[0];
        out[node * OUT_DIM + 1] = di * (a1 + self.y) + b2[1];
    }
}

extern "C" void kernel_launch(void* const* d_in, const int* in_sizes, int n_in,
                              void* d_out, int out_size, void* d_ws, size_t ws_size,
                              hipStream_t stream) {
    const float* x  = (const float*)d_in[0];
    const int*   ei = (const int*)d_in[1];     // [2][E], row 0 = src, row 1 = dst
    const float* W1 = (const float*)d_in[2];
    const float* b1 = (const float*)d_in[3];
    const float* W2 = (const float*)d_in[4];
    const float* b2 = (const float*)d_in[5];
    float* out = (float*)d_out;

    const int n = N_NODES;
    const int E = in_sizes[1] / 2;

    char* ws = (char*)d_ws;
    int*   gCursor = (int*)  (ws + 0);            // 3.1 KB
    int*   cnt     = (int*)  (ws + (1u << 20));   // 400 KB
    float* dinv    = (float*)(ws + (2u << 20));   // 400 KB
    int*   rowptr  = (int*)  (ws + (3u << 20));   // 400 KB
    float* hs2     = (float*)(ws + (4u << 20));   // 800 KB
    int*   part    = (int*)  (ws + (5u << 20));   // NB*BCAP*4 = 16.0 MB
    int*   csr_src = (int*)  (ws + (22u << 20));  // NB*BCAP*4 = 16.0 MB
    unsigned short* hsb = (unsigned short*)(ws + (39u << 20));  // 12.8 MB

    hipMemsetAsync(gCursor, 0, NB * sizeof(int), stream);

    part_kernel<<<(E + CHUNK - 1) / CHUNK, 1024, 0, stream>>>(ei, gCursor, part, E);
    degs_kernel<<<NB, 256, 0, stream>>>(part, gCursor, dinv, n);

    gemm1_kernel<<<(n + 63) / 64, 256, 0, stream>>>(x, W1, dinv, hsb, n);
    aggsort_kernel<<<NB, 512, 0, stream>>>(part, gCursor, hsb, dinv, b1, W2,
                                           cnt, rowptr, csr_src, hs2, n);
    agg2_kernel<<<(n + 7) / 8, 256, 0, stream>>>(rowptr, cnt, csr_src, hs2, dinv, b2, out, n);
}